// Round 4
// baseline (266.249 us; speedup 1.0000x reference)
//
#include <hip/hip_runtime.h>
#include <math.h>

#define BB 512
#define DD 512
#define KK 93431
#define KPAD 93440

#define S_SCALEf 64.0f
#define COS_Mf   0.87758256189037276f   /* cos(0.5) */
#define SIN_Mf   0.47942553860420301f   /* sin(0.5) */
#define THRESHf (-0.87758256189037276f) /* cos(pi-0.5) */
#define MMf      0.23971276930210151f   /* sin(pi-0.5)*0.5 */
#define EPSf     0.1f
#define MFIXf    65.0f

typedef __bf16 bf16x8 __attribute__((ext_vector_type(8)));
typedef float  f32x4  __attribute__((ext_vector_type(4)));
typedef unsigned short ushort8 __attribute__((ext_vector_type(8)));

__device__ __forceinline__ unsigned short f2bf(float f) {
    union { float f; unsigned u; } v; v.f = f;
    unsigned r = v.u + 0x7FFFu + ((v.u >> 16) & 1u);   // RNE
    return (unsigned short)(r >> 16);
}

__device__ __forceinline__ void gload16(const void* g, void* l) {
    __builtin_amdgcn_global_load_lds(
        (const __attribute__((address_space(1))) unsigned int*)g,
        (__attribute__((address_space(3))) unsigned int*)l, 16, 0, 0);
}

// ---- kernel 1: row-normalize x -> xn (f32) + xnf (bf16, MFMA-fragment order) ----
// xnf layout: 16B chunk index = ((w*4 + f)*16 + ks)*64 + lane
//   row r = w*64 + f*16 + (lane&15); k-bytes = ks*64 + (lane>>4)*16
__global__ void rownorm_k(const float* __restrict__ x, float* __restrict__ xn,
                          unsigned short* __restrict__ xnf) {
    int b = blockIdx.x;
    int t = threadIdx.x; // 256
    float v0 = x[b * DD + t];
    float v1 = x[b * DD + t + 256];
    float ss = v0 * v0 + v1 * v1;
    for (int off = 32; off; off >>= 1) ss += __shfl_down(ss, off);
    __shared__ float wred[4];
    __shared__ float s_inv;
    __shared__ unsigned short rb[512];
    if ((t & 63) == 0) wred[t >> 6] = ss;
    __syncthreads();
    if (t == 0) s_inv = rsqrtf(wred[0] + wred[1] + wred[2] + wred[3]);
    __syncthreads();
    float inv = s_inv;
    float a0 = v0 * inv, a1 = v1 * inv;
    xn[b * DD + t]       = a0;
    xn[b * DD + t + 256] = a1;
    rb[t]       = f2bf(a0);
    rb[t + 256] = f2bf(a1);
    __syncthreads();
    if (t < 64) {
        int c = t;                       // 16B chunk of this row (8 bf16)
        int w = b >> 6, f = (b >> 4) & 3;
        int ks = c >> 2, ln = (b & 15) + ((c & 3) << 4);
        ushort8 o;
#pragma unroll
        for (int e = 0; e < 8; ++e) o[e] = rb[c * 8 + e];
        reinterpret_cast<ushort8*>(xnf)[((w * 4 + f) * 16 + ks) * 64 + ln] = o;
    }
}

// ------------- kernel 2: transpose+convert kernel matrix, partial column sumsq -------
__global__ __launch_bounds__(256) void tcvt_k(const float* __restrict__ ker,
                                              unsigned short* __restrict__ kerbt,
                                              float* __restrict__ ssq) {
    __shared__ float tile[64][65];
    __shared__ float sp[256];
    int t = threadIdx.x;
    int c0 = blockIdx.x * 64;
    int d0 = blockIdx.y * 64;
    int lc = t & 63;
    int dq = t >> 6;
    int gc = c0 + lc;
    bool valid = gc < KK;
    float ss = 0.f;
#pragma unroll
    for (int i = 0; i < 16; ++i) {
        int d = dq + i * 4;
        float v = valid ? ker[(size_t)(d0 + d) * KK + gc] : 0.f;
        tile[d][lc] = v;
        ss = fmaf(v, v, ss);
    }
    sp[t] = ss;
    __syncthreads();
    if (t < 64 && (c0 + t) < KK) {
        float tot = sp[t] + sp[t + 64] + sp[t + 128] + sp[t + 192];
        atomicAdd(&ssq[c0 + t], tot);
    }
#pragma unroll
    for (int j = 0; j < 2; ++j) {
        int l = t + 256 * j;
        int c = l >> 3;
        int dc = l & 7;
        ushort8 o;
#pragma unroll
        for (int e = 0; e < 8; ++e) o[e] = f2bf(tile[dc * 8 + e][c]);
        *reinterpret_cast<ushort8*>(&kerbt[(size_t)(c0 + c) * DD + d0 + dc * 8]) = o;
    }
}

// ---------------- kernel 3: target logits (label columns, fp32) ----------------
__global__ void target_k(const float* __restrict__ xn, const float* __restrict__ ker,
                         const float* __restrict__ ssq, const int* __restrict__ label,
                         float* __restrict__ tl) {
    int b = blockIdx.x;
    int lane = threadIdx.x; // 64
    int col = label[b];
    float acc = 0.f;
#pragma unroll
    for (int d = lane; d < DD; d += 64)
        acc = fmaf(xn[b * DD + d], ker[(size_t)d * KK + col], acc);
    for (int off = 32; off; off >>= 1) acc += __shfl_down(acc, off);
    if (lane == 0) {
        float c = acc * rsqrtf(ssq[col]);
        c = fminf(1.f, fmaxf(-1.f, c));
        tl[b] = c;
    }
}

// ---------------- kernel 4: scalars (t_new, cos_theta_m, final target) ----------
__global__ void scalar_k(const float* __restrict__ tl, const float* __restrict__ t_in,
                         float* __restrict__ ctm, float* __restrict__ ftl,
                         float* __restrict__ tnew) {
    int t = threadIdx.x; // 512
    float v = tl[t];
    __shared__ float red[8];
    __shared__ float s_tn;
    float s = v;
    for (int off = 32; off; off >>= 1) s += __shfl_down(s, off);
    if ((t & 63) == 0) red[t >> 6] = s;
    __syncthreads();
    if (t == 0) {
        float tot = 0.f;
        for (int i = 0; i < 8; ++i) tot += red[i];
        s_tn = (tot / 512.0f) * 0.01f + 0.99f * t_in[0];
        tnew[0] = s_tn;
    }
    __syncthreads();
    float st = sqrtf(fmaxf(0.f, 1.f - v * v));
    float cm = v * COS_Mf - st * SIN_Mf;
    ctm[t] = cm;
    ftl[t] = (v > THRESHf) ? cm : (v - MMf);
}

// ---- kernel 5: A-in-registers streaming GEMM + CurricularFace epilogue ----
// grid = 256 persistent blocks (1/CU), 512 threads = 8 waves, BM = 512 (full M),
// BN = 64 cols/panel, full K = 512 per panel.  B staged ONCE device-wide.
#define BN 64
#define NPAN (KPAD / BN)        /* 1460 */
#define GEMM_GRID 256

__global__ __launch_bounds__(512) void gemm_k(
    const __bf16* __restrict__ xnf,            // A fragments (fragment-order)
    const unsigned short* __restrict__ kerbt,  // [KPAD][512] bf16
    const float* __restrict__ ssq,
    const int* __restrict__ label,
    const float* __restrict__ ctm, const float* __restrict__ ftl,
    const float* __restrict__ tnew,
    float* __restrict__ gse, float* __restrict__ gsl)
{
    __shared__ __align__(16) unsigned short Bs[2][BN * DD];  // 2 x 64 KB
    __shared__ float se_s[512], sl_s[512], ctm_s[512], ftl_s[512];
    __shared__ int   lbl_s[512];

    const int t = threadIdx.x;        // 512
    const int lane = t & 63;
    const int w = t >> 6;             // wave owns rows w*64..w*64+63
    const int blk = blockIdx.x;
    const int cp0 = lane & 15;
    const int kq = lane >> 4;

    se_s[t] = 0.f; sl_s[t] = 0.f;
    ctm_s[t] = ctm[t]; ftl_s[t] = ftl[t]; lbl_s[t] = label[t];
    const float tn = tnew[0];

    // ---- A fragments: 64 rows x 512 k per wave, 256 VGPRs, loaded once ----
    bf16x8 a_reg[4][16];
    {
        const bf16x8* xf = reinterpret_cast<const bf16x8*>(xnf);
#pragma unroll
        for (int f = 0; f < 4; ++f)
#pragma unroll
            for (int ks = 0; ks < 16; ++ks)
                a_reg[f][ks] = xf[((w * 4 + f) * 16 + ks) * 64 + lane];
    }
    // force completion here so no vmcnt waits land inside the panel loop
#pragma unroll
    for (int f = 0; f < 4; ++f)
#pragma unroll
        for (int ks = 0; ks < 16; ++ks)
            asm volatile("" :: "v"(__builtin_bit_cast(f32x4, a_reg[f][ks])));

    // ---- prologue: stage first panel into buffer 0 ----
    {
        const int col0 = blk * BN;
#pragma unroll
        for (int j = 0; j < 8; ++j) {
            int l = t + 512 * j;              // 0..4095 16B-chunks
            int c = l >> 6, kc = l & 63;
            int kcs = kc ^ (c & 7);           // source pre-swizzle (T2, rule 21)
            gload16(&kerbt[(size_t)(col0 + c) * DD + kcs * 8], (void*)&Bs[0][l * 8]);
        }
    }

    int buf = 0;
    for (int p = blk; p < NPAN; p += GEMM_GRID) {
        const int col0 = p * BN;
        // per-panel column params — issued BEFORE next stage so their auto-wait
        // doesn't drain the staging queue
        float inv4[4], ok4[4]; int col4[4];
#pragma unroll
        for (int fc = 0; fc < 4; ++fc) {
            int c = col0 + fc * 16 + cp0;
            col4[fc] = c;
            float sq = ssq[c];
            ok4[fc] = (c < KK) ? 1.f : 0.f;
            inv4[fc] = (c < KK) ? rsqrtf(sq) : 0.f;
        }

        const int pn = p + GEMM_GRID;
        if (pn < NPAN) {
            const int cn0 = pn * BN;
#pragma unroll
            for (int j = 0; j < 8; ++j) {
                int l = t + 512 * j;
                int c = l >> 6, kc = l & 63;
                int kcs = kc ^ (c & 7);
                gload16(&kerbt[(size_t)(cn0 + c) * DD + kcs * 8],
                        (void*)&Bs[buf ^ 1][l * 8]);
            }
            __builtin_amdgcn_sched_barrier(0);
            asm volatile("s_waitcnt vmcnt(8)" ::: "memory");  // panel p landed
        } else {
            asm volatile("s_waitcnt vmcnt(0)" ::: "memory");
        }
        __builtin_amdgcn_s_barrier();
        __builtin_amdgcn_sched_barrier(0);

        // ---- compute panel p: 256 MFMA, 64 ds_read_b128 per wave ----
        f32x4 acc[4][4];
#pragma unroll
        for (int fm = 0; fm < 4; ++fm)
#pragma unroll
            for (int fc = 0; fc < 4; ++fc) acc[fm][fc] = (f32x4)0.f;

        const char* Bp = (const char*)&Bs[buf][0];
        __builtin_amdgcn_s_setprio(1);
#pragma unroll
        for (int ks = 0; ks < 16; ++ks) {
            bf16x8 bfr[4];
#pragma unroll
            for (int fc = 0; fc < 4; ++fc) {
                int cp = fc * 16 + cp0;
                int kk = ks * 4 + kq;
                int off = cp * 1024 + ((kk ^ (cp & 7)) * 16);  // read-side swizzle
                bfr[fc] = *reinterpret_cast<const bf16x8*>(Bp + off);
            }
#pragma unroll
            for (int fm = 0; fm < 4; ++fm)
#pragma unroll
                for (int fc = 0; fc < 4; ++fc)
                    acc[fm][fc] = __builtin_amdgcn_mfma_f32_16x16x32_bf16(
                        a_reg[fm][ks], bfr[fc], acc[fm][fc], 0, 0, 0);
        }
        __builtin_amdgcn_s_setprio(0);

        // ---- fused CurricularFace epilogue for this panel ----
#pragma unroll
        for (int fm = 0; fm < 4; ++fm) {
#pragma unroll
            for (int reg = 0; reg < 4; ++reg) {
                int rowl = w * 64 + fm * 16 + (kq << 2) + reg;
                float cm = ctm_s[rowl], ft = ftl_s[rowl];
                int lbl = lbl_s[rowl];
                float se = 0.f, sl = 0.f;
#pragma unroll
                for (int fc = 0; fc < 4; ++fc) {
                    float c = acc[fm][fc][reg] * inv4[fc];
                    c = fminf(1.f, fmaxf(-1.f, c));
                    float v = (c > cm) ? c * (tn + c) : c;
                    if (col4[fc] == lbl) v = ft;
                    float lg = S_SCALEf * v;
                    se += ok4[fc] * __expf(lg - MFIXf);
                    sl += ok4[fc] * lg;
                }
#pragma unroll
                for (int off = 8; off; off >>= 1) {
                    se += __shfl_down(se, off, 16);
                    sl += __shfl_down(sl, off, 16);
                }
                if (cp0 == 0) {
                    atomicAdd(&se_s[rowl], se);   // LDS, contention-free
                    atomicAdd(&sl_s[rowl], sl);
                }
            }
        }
        __builtin_amdgcn_s_barrier();   // all reads of buf done before overwrite
        buf ^= 1;
    }

    __syncthreads();
    atomicAdd(&gse[t], se_s[t]);
    atomicAdd(&gsl[t], sl_s[t]);
}

// ---------------- kernel 6: final loss ----------------
__global__ void loss_k(const float* __restrict__ gse, const float* __restrict__ gsl,
                       const float* __restrict__ ftl, float* __restrict__ out) {
    int t = threadIdx.x; // 512
    float lse = MFIXf + logf(gse[t]);
    float lbl_logit = S_SCALEf * ftl[t];
    float nll = (1.f - EPSf) * (lbl_logit - lse)
              + (EPSf / (float)KK) * (gsl[t] - (float)KK * lse);
    __shared__ float red[8];
    float s = nll;
    for (int off = 32; off; off >>= 1) s += __shfl_down(s, off);
    if ((t & 63) == 0) red[t >> 6] = s;
    __syncthreads();
    if (t == 0) {
        float tot = 0.f;
        for (int i = 0; i < 8; ++i) tot += red[i];
        out[0] = -(tot / 512.0f);
    }
}

extern "C" void kernel_launch(void* const* d_in, const int* in_sizes, int n_in,
                              void* d_out, int out_size, void* d_ws, size_t ws_size,
                              hipStream_t stream) {
    const float* x     = (const float*)d_in[0];
    const int*   label = (const int*)d_in[1];
    const float* ker   = (const float*)d_in[2];
    const float* t_in  = (const float*)d_in[3];
    float* out = (float*)d_out;

    float* ws   = (float*)d_ws;
    float* xn   = ws;                 // 262144 f32
    float* ssq  = xn + 262144;        // KPAD
    float* gse  = ssq + KPAD;         // 512
    float* gsl  = gse + 512;          // 512
    float* tl   = gsl + 512;          // 512
    float* ctm  = tl + 512;           // 512
    float* ftl  = ctm + 512;          // 512
    float* tnew = ftl + 512;          // 64
    unsigned short* xnf   = (unsigned short*)(tnew + 64);    // 262144 bf16 (frag order)
    unsigned short* kerbt = xnf + 262144;                    // KPAD*512 bf16

    hipMemsetAsync(ssq, 0, (KPAD + 1024) * sizeof(float), stream);

    rownorm_k<<<BB, 256, 0, stream>>>(x, xn, xnf);
    tcvt_k<<<dim3(KPAD / 64, DD / 64), 256, 0, stream>>>(ker, kerbt, ssq);
    target_k<<<BB, 64, 0, stream>>>(xn, ker, ssq, label, tl);
    scalar_k<<<1, 512, 0, stream>>>(tl, t_in, ctm, ftl, tnew);
    gemm_k<<<GEMM_GRID, 512, 0, stream>>>((const __bf16*)xnf, kerbt, ssq, label,
                                          ctm, ftl, tnew, gse, gsl);
    loss_k<<<1, 512, 0, stream>>>(gse, gsl, ftl, out);
}

// Round 5
// 223.295 us; speedup vs baseline: 1.1924x; 1.1924x over previous
//
#include <hip/hip_runtime.h>
#include <math.h>

#define BB 512
#define DD 512
#define KK 93431
#define KPAD 93440

#define S_SCALEf 64.0f
#define COS_Mf   0.87758256189037276f   /* cos(0.5) */
#define SIN_Mf   0.47942553860420301f   /* sin(0.5) */
#define THRESHf (-0.87758256189037276f) /* cos(pi-0.5) */
#define MMf      0.23971276930210151f   /* sin(pi-0.5)*0.5 */
#define EPSf     0.1f
#define MFIXf    65.0f

typedef __bf16 bf16x8 __attribute__((ext_vector_type(8)));
typedef float  f32x4  __attribute__((ext_vector_type(4)));
typedef unsigned short ushort8 __attribute__((ext_vector_type(8)));

__device__ __forceinline__ unsigned short f2bf(float f) {
    union { float f; unsigned u; } v; v.f = f;
    unsigned r = v.u + 0x7FFFu + ((v.u >> 16) & 1u);   // RNE
    return (unsigned short)(r >> 16);
}

__device__ __forceinline__ void gload16(const void* g, void* l) {
    __builtin_amdgcn_global_load_lds(
        (const __attribute__((address_space(1))) unsigned int*)g,
        (__attribute__((address_space(3))) unsigned int*)l, 16, 0, 0);
}

// ---- kernel 1: row-normalize x -> xn (f32) + xnf (bf16, MFMA-fragment order) ----
// xnf 16B-chunk index = (g16 * 16 + ks) * 64 + ln, where g16 = row/16,
// ln = (row&15) + (kquad<<4), ks = k-chunk/4.  (frag for 16x16x32 A operand)
__global__ void rownorm_k(const float* __restrict__ x, float* __restrict__ xn,
                          unsigned short* __restrict__ xnf) {
    int b = blockIdx.x;
    int t = threadIdx.x; // 256
    float v0 = x[b * DD + t];
    float v1 = x[b * DD + t + 256];
    float ss = v0 * v0 + v1 * v1;
    for (int off = 32; off; off >>= 1) ss += __shfl_down(ss, off);
    __shared__ float wred[4];
    __shared__ float s_inv;
    __shared__ unsigned short rb[512];
    if ((t & 63) == 0) wred[t >> 6] = ss;
    __syncthreads();
    if (t == 0) s_inv = rsqrtf(wred[0] + wred[1] + wred[2] + wred[3]);
    __syncthreads();
    float inv = s_inv;
    float a0 = v0 * inv, a1 = v1 * inv;
    xn[b * DD + t]       = a0;
    xn[b * DD + t + 256] = a1;
    rb[t]       = f2bf(a0);
    rb[t + 256] = f2bf(a1);
    __syncthreads();
    if (t < 64) {
        int c = t;                       // 16B chunk of this row (8 bf16)
        int g16 = b >> 4;
        int ks = c >> 2, ln = (b & 15) + ((c & 3) << 4);
        ushort8 o;
#pragma unroll
        for (int e = 0; e < 8; ++e) o[e] = rb[c * 8 + e];
        reinterpret_cast<ushort8*>(xnf)[(g16 * 16 + ks) * 64 + ln] = o;
    }
}

// ------------- kernel 2: transpose+convert kernel matrix, partial column sumsq -------
__global__ __launch_bounds__(256) void tcvt_k(const float* __restrict__ ker,
                                              unsigned short* __restrict__ kerbt,
                                              float* __restrict__ ssq) {
    __shared__ float tile[64][65];
    __shared__ float sp[256];
    int t = threadIdx.x;
    int c0 = blockIdx.x * 64;
    int d0 = blockIdx.y * 64;
    int lc = t & 63;
    int dq = t >> 6;
    int gc = c0 + lc;
    bool valid = gc < KK;
    float ss = 0.f;
#pragma unroll
    for (int i = 0; i < 16; ++i) {
        int d = dq + i * 4;
        float v = valid ? ker[(size_t)(d0 + d) * KK + gc] : 0.f;
        tile[d][lc] = v;
        ss = fmaf(v, v, ss);
    }
    sp[t] = ss;
    __syncthreads();
    if (t < 64 && (c0 + t) < KK) {
        float tot = sp[t] + sp[t + 64] + sp[t + 128] + sp[t + 192];
        atomicAdd(&ssq[c0 + t], tot);
    }
#pragma unroll
    for (int j = 0; j < 2; ++j) {
        int l = t + 256 * j;
        int c = l >> 3;
        int dc = l & 7;
        ushort8 o;
#pragma unroll
        for (int e = 0; e < 8; ++e) o[e] = f2bf(tile[dc * 8 + e][c]);
        *reinterpret_cast<ushort8*>(&kerbt[(size_t)(c0 + c) * DD + d0 + dc * 8]) = o;
    }
}

// ---------------- kernel 3: target logits (label columns, fp32) ----------------
__global__ void target_k(const float* __restrict__ xn, const float* __restrict__ ker,
                         const float* __restrict__ ssq, const int* __restrict__ label,
                         float* __restrict__ tl) {
    int b = blockIdx.x;
    int lane = threadIdx.x; // 64
    int col = label[b];
    float acc = 0.f;
#pragma unroll
    for (int d = lane; d < DD; d += 64)
        acc = fmaf(xn[b * DD + d], ker[(size_t)d * KK + col], acc);
    for (int off = 32; off; off >>= 1) acc += __shfl_down(acc, off);
    if (lane == 0) {
        float c = acc * rsqrtf(ssq[col]);
        c = fminf(1.f, fmaxf(-1.f, c));
        tl[b] = c;
    }
}

// ------- kernel 4: scalars (t_new, cos_theta_m, final target) + ssq pad fix -------
__global__ void scalar_k(const float* __restrict__ tl, const float* __restrict__ t_in,
                         float* __restrict__ ctm, float* __restrict__ ftl,
                         float* __restrict__ tnew, float* __restrict__ ssq) {
    int t = threadIdx.x; // 512
    float v = tl[t];
    __shared__ float red[8];
    __shared__ float s_tn;
    float s = v;
    for (int off = 32; off; off >>= 1) s += __shfl_down(s, off);
    if ((t & 63) == 0) red[t >> 6] = s;
    __syncthreads();
    if (t == 0) {
        float tot = 0.f;
        for (int i = 0; i < 8; ++i) tot += red[i];
        s_tn = (tot / 512.0f) * 0.01f + 0.99f * t_in[0];
        tnew[0] = s_tn;
    }
    __syncthreads();
    float st = sqrtf(fmaxf(0.f, 1.f - v * v));
    float cm = v * COS_Mf - st * SIN_Mf;
    ctm[t] = cm;
    ftl[t] = (v > THRESHf) ? cm : (v - MMf);
    if (t < KPAD - KK) ssq[KK + t] = 1.f;   // pad cols: kerbt rows are 0 -> logit 0
}

// ---- kernel 5: A-in-registers (32 rows/wave) streaming GEMM + fused epilogue ----
// grid = 512 blocks: h = blk>>8 (row half), s = blk&255 (panel stream).
// Block = 8 waves x 32 rows = 256 rows; B panels (64 cols x 512 k) double-buffered
// in LDS, staged once per row-half device-wide.  a_reg = 128 VGPR/wave.
#define BNp 64
#define NPAN (KPAD / BNp)       /* 1460 */
#define NSTR 256

__global__ __launch_bounds__(512, 2) void gemm_k(
    const __bf16* __restrict__ xnf,            // A fragments (fragment-order)
    const unsigned short* __restrict__ kerbt,  // [KPAD][512] bf16
    const float* __restrict__ ssq,
    const int* __restrict__ label,
    const float* __restrict__ ctm, const float* __restrict__ ftl,
    const float* __restrict__ tnew,
    float* __restrict__ gse, float* __restrict__ gsl)
{
    __shared__ __align__(16) unsigned short Bs[2][BNp * DD];  // 2 x 64 KB
    __shared__ float ctm_s[256], ftl_s[256];
    __shared__ int   lbl_s[256];

    const int t = threadIdx.x;        // 512
    const int lane = t & 63;
    const int w = t >> 6;             // wave owns rows h*256 + w*32 .. +31
    const int h = blockIdx.x >> 8;    // row half (0/1)
    const int s = blockIdx.x & 255;   // panel stream
    const int cp0 = lane & 15;
    const int kq = lane >> 4;
    const int np = (s < NPAN - 5 * NSTR) ? 6 : 5;   // panels in this stream

    if (t < 256) {
        int r = h * 256 + t;
        ctm_s[t] = ctm[r]; ftl_s[t] = ftl[r]; lbl_s[t] = label[r];
    }
    const float tn = tnew[0];

    // ---- A fragments: 32 rows x 512 k per wave = 128 VGPRs, loaded once ----
    bf16x8 a_reg[2][16];
    {
        const bf16x8* xf = reinterpret_cast<const bf16x8*>(xnf);
        const int g0 = h * 16 + w * 2;
#pragma unroll
        for (int i = 0; i < 2; ++i)
#pragma unroll
            for (int ks = 0; ks < 16; ++ks)
                a_reg[i][ks] = xf[((g0 + i) * 16 + ks) * 64 + lane];
    }
    __builtin_amdgcn_sched_barrier(0);

    // ---- prologue: stage panel s -> buf0, params for s, panel s+256 -> buf1 ----
#pragma unroll
    for (int j = 0; j < 8; ++j) {
        int l = t + 512 * j;              // 0..4095 16B-chunks
        int c = l >> 6, kc = l & 63;
        int kcs = kc ^ (c & 7);           // source pre-swizzle
        gload16(&kerbt[(size_t)(s * BNp + c) * DD + kcs * 8], (void*)&Bs[0][l * 8]);
    }
    float sqN[4]; int colN[4];
#pragma unroll
    for (int fc = 0; fc < 4; ++fc) {
        colN[fc] = s * BNp + fc * 16 + cp0;
        sqN[fc] = ssq[colN[fc]];
    }
    if (np > 1) {
#pragma unroll
        for (int j = 0; j < 8; ++j) {
            int l = t + 512 * j;
            int c = l >> 6, kc = l & 63;
            int kcs = kc ^ (c & 7);
            gload16(&kerbt[(size_t)((s + NSTR) * BNp + c) * DD + kcs * 8],
                    (void*)&Bs[1][l * 8]);
        }
        __builtin_amdgcn_sched_barrier(0);
        asm volatile("s_waitcnt vmcnt(8)" ::: "memory");
    } else {
        __builtin_amdgcn_sched_barrier(0);
        asm volatile("s_waitcnt vmcnt(0)" ::: "memory");
    }
    float inv4[4]; int col4[4];
#pragma unroll
    for (int fc = 0; fc < 4; ++fc) { inv4[fc] = rsqrtf(sqN[fc]); col4[fc] = colN[fc]; }
    __builtin_amdgcn_s_barrier();

    float regse[2][4], regsl[2][4];
#pragma unroll
    for (int i = 0; i < 2; ++i)
#pragma unroll
        for (int r = 0; r < 4; ++r) { regse[i][r] = 0.f; regsl[i][r] = 0.f; }

    int buf = 0;
    for (int pi = 0; pi < np; ++pi) {
        // 1. prefetch next panel's column params (drained by this iter's vmcnt)
        if (pi + 1 < np) {
            const int cn0 = (s + (pi + 1) * NSTR) * BNp;
#pragma unroll
            for (int fc = 0; fc < 4; ++fc) {
                colN[fc] = cn0 + fc * 16 + cp0;
                sqN[fc] = ssq[colN[fc]];
            }
        }

        // 2. compute panel: 128 MFMA + 64 ds_read_b128 per wave
        f32x4 acc[2][4];
#pragma unroll
        for (int i = 0; i < 2; ++i)
#pragma unroll
            for (int fc = 0; fc < 4; ++fc) acc[i][fc] = (f32x4)0.f;

        const char* Bp = (const char*)&Bs[buf][0];
        __builtin_amdgcn_s_setprio(1);
#pragma unroll
        for (int ks = 0; ks < 16; ++ks) {
            bf16x8 bfr[4];
#pragma unroll
            for (int fc = 0; fc < 4; ++fc) {
                int cp = fc * 16 + cp0;
                int kk = ks * 4 + kq;
                int off = cp * 1024 + ((kk ^ (cp & 7)) * 16);  // read-side swizzle
                bfr[fc] = *reinterpret_cast<const bf16x8*>(Bp + off);
            }
#pragma unroll
            for (int i = 0; i < 2; ++i)
#pragma unroll
                for (int fc = 0; fc < 4; ++fc)
                    acc[i][fc] = __builtin_amdgcn_mfma_f32_16x16x32_bf16(
                        a_reg[i][ks], bfr[fc], acc[i][fc], 0, 0, 0);
        }
        __builtin_amdgcn_s_setprio(0);

        // fused CurricularFace transform; per-lane partials stay in registers
#pragma unroll
        for (int i = 0; i < 2; ++i) {
#pragma unroll
            for (int r = 0; r < 4; ++r) {
                const int rowl = w * 32 + i * 16 + (kq << 2) + r;
                float cm = ctm_s[rowl], ft = ftl_s[rowl];
                int lbl = lbl_s[rowl];
                float se = 0.f, sl = 0.f;
#pragma unroll
                for (int fc = 0; fc < 4; ++fc) {
                    float c = acc[i][fc][r] * inv4[fc];
                    c = fminf(1.f, fmaxf(-1.f, c));
                    float v = (c > cm) ? c * (tn + c) : c;
                    if (col4[fc] == lbl) v = ft;
                    float lg = S_SCALEf * v;
                    se += __expf(lg - MFIXf);
                    sl += lg;
                }
                regse[i][r] += se;
                regsl[i][r] += sl;
            }
        }

        // 3. all waves done reading buf -> safe to overwrite
        __builtin_amdgcn_s_barrier();
        if (pi + 2 < np) {
            const int cn0 = (s + (pi + 2) * NSTR) * BNp;
#pragma unroll
            for (int j = 0; j < 8; ++j) {
                int l = t + 512 * j;
                int c = l >> 6, kc = l & 63;
                int kcs = kc ^ (c & 7);
                gload16(&kerbt[(size_t)(cn0 + c) * DD + kcs * 8],
                        (void*)&Bs[buf][l * 8]);
            }
            __builtin_amdgcn_sched_barrier(0);
            asm volatile("s_waitcnt vmcnt(8)" ::: "memory");  // panel pi+1 landed
        } else if (pi + 1 < np) {
            asm volatile("s_waitcnt vmcnt(0)" ::: "memory");
        }
        if (pi + 1 < np) {
#pragma unroll
            for (int fc = 0; fc < 4; ++fc) {
                inv4[fc] = rsqrtf(sqN[fc]);
                col4[fc] = colN[fc];
            }
            __builtin_amdgcn_s_barrier();
        }
        buf ^= 1;
    }

    // ---- block-end reduction: 16 lanes -> row, one global atomic per row ----
#pragma unroll
    for (int i = 0; i < 2; ++i) {
#pragma unroll
        for (int r = 0; r < 4; ++r) {
            float se = regse[i][r], sl = regsl[i][r];
#pragma unroll
            for (int off = 8; off; off >>= 1) {
                se += __shfl_down(se, off, 16);
                sl += __shfl_down(sl, off, 16);
            }
            if (cp0 == 0) {
                const int row = h * 256 + w * 32 + i * 16 + (kq << 2) + r;
                atomicAdd(&gse[row], se);
                atomicAdd(&gsl[row], sl);
            }
        }
    }
}

// ---------------- kernel 6: final loss ----------------
__global__ void loss_k(const float* __restrict__ gse, const float* __restrict__ gsl,
                       const float* __restrict__ ftl, float* __restrict__ out) {
    int t = threadIdx.x; // 512
    float lse = MFIXf + logf(gse[t]);
    float lbl_logit = S_SCALEf * ftl[t];
    float nll = (1.f - EPSf) * (lbl_logit - lse)
              + (EPSf / (float)KK) * (gsl[t] - (float)KK * lse);
    __shared__ float red[8];
    float s = nll;
    for (int off = 32; off; off >>= 1) s += __shfl_down(s, off);
    if ((t & 63) == 0) red[t >> 6] = s;
    __syncthreads();
    if (t == 0) {
        float tot = 0.f;
        for (int i = 0; i < 8; ++i) tot += red[i];
        out[0] = -(tot / 512.0f);
    }
}

extern "C" void kernel_launch(void* const* d_in, const int* in_sizes, int n_in,
                              void* d_out, int out_size, void* d_ws, size_t ws_size,
                              hipStream_t stream) {
    const float* x     = (const float*)d_in[0];
    const int*   label = (const int*)d_in[1];
    const float* ker   = (const float*)d_in[2];
    const float* t_in  = (const float*)d_in[3];
    float* out = (float*)d_out;

    float* ws   = (float*)d_ws;
    float* xn   = ws;                 // 262144 f32
    float* ssq  = xn + 262144;        // KPAD
    float* gse  = ssq + KPAD;         // 512
    float* gsl  = gse + 512;          // 512
    float* tl   = gsl + 512;          // 512
    float* ctm  = tl + 512;           // 512
    float* ftl  = ctm + 512;          // 512
    float* tnew = ftl + 512;          // 64
    unsigned short* xnf   = (unsigned short*)(tnew + 64);    // 262144 bf16 (frag order)
    unsigned short* kerbt = xnf + 262144;                    // KPAD*512 bf16

    hipMemsetAsync(ssq, 0, (KPAD + 1024) * sizeof(float), stream);

    rownorm_k<<<BB, 256, 0, stream>>>(x, xn, xnf);
    tcvt_k<<<dim3(KPAD / 64, DD / 64), 256, 0, stream>>>(ker, kerbt, ssq);
    target_k<<<BB, 64, 0, stream>>>(xn, ker, ssq, label, tl);
    scalar_k<<<1, 512, 0, stream>>>(tl, t_in, ctm, ftl, tnew, ssq);
    gemm_k<<<512, 512, 0, stream>>>((const __bf16*)xnf, kerbt, ssq, label,
                                    ctm, ftl, tnew, gse, gsl);
    loss_k<<<1, 512, 0, stream>>>(gse, gsl, ftl, out);
}

// Round 6
// 210.116 us; speedup vs baseline: 1.2672x; 1.0627x over previous
//
#include <hip/hip_runtime.h>
#include <math.h>

#define BB 512
#define DD 512
#define KK 93431
#define KPAD 93440

#define S_SCALEf 64.0f
#define COS_Mf   0.87758256189037276f   /* cos(0.5) */
#define SIN_Mf   0.47942553860420301f   /* sin(0.5) */
#define THRESHf (-0.87758256189037276f) /* cos(pi-0.5) */
#define MMf      0.23971276930210151f   /* sin(pi-0.5)*0.5 */
#define EPSf     0.1f
#define MFIXf    65.0f

typedef __bf16 bf16x8 __attribute__((ext_vector_type(8)));
typedef float  f32x4  __attribute__((ext_vector_type(4)));
typedef unsigned short ushort8 __attribute__((ext_vector_type(8)));

__device__ __forceinline__ unsigned short f2bf(float f) {
    union { float f; unsigned u; } v; v.f = f;
    unsigned r = v.u + 0x7FFFu + ((v.u >> 16) & 1u);   // RNE
    return (unsigned short)(r >> 16);
}

__device__ __forceinline__ void gload16(const void* g, void* l) {
    __builtin_amdgcn_global_load_lds(
        (const __attribute__((address_space(1))) unsigned int*)g,
        (__attribute__((address_space(3))) unsigned int*)l, 16, 0, 0);
}

// ---- kernel 1: row-normalize x -> xn (f32) + xnf (bf16, MFMA-fragment order) ----
// xnf 16B-chunk index = (g16 * 16 + ks) * 64 + ln, where g16 = row/16,
// ln = (row&15) + (kquad<<4), ks = k-chunk/4.  (frag for 16x16x32 A operand)
__global__ void rownorm_k(const float* __restrict__ x, float* __restrict__ xn,
                          unsigned short* __restrict__ xnf) {
    int b = blockIdx.x;
    int t = threadIdx.x; // 256
    float v0 = x[b * DD + t];
    float v1 = x[b * DD + t + 256];
    float ss = v0 * v0 + v1 * v1;
    for (int off = 32; off; off >>= 1) ss += __shfl_down(ss, off);
    __shared__ float wred[4];
    __shared__ float s_inv;
    __shared__ unsigned short rb[512];
    if ((t & 63) == 0) wred[t >> 6] = ss;
    __syncthreads();
    if (t == 0) s_inv = rsqrtf(wred[0] + wred[1] + wred[2] + wred[3]);
    __syncthreads();
    float inv = s_inv;
    float a0 = v0 * inv, a1 = v1 * inv;
    xn[b * DD + t]       = a0;
    xn[b * DD + t + 256] = a1;
    rb[t]       = f2bf(a0);
    rb[t + 256] = f2bf(a1);
    __syncthreads();
    if (t < 64) {
        int c = t;                       // 16B chunk of this row (8 bf16)
        int g16 = b >> 4;
        int ks = c >> 2, ln = (b & 15) + ((c & 3) << 4);
        ushort8 o;
#pragma unroll
        for (int e = 0; e < 8; ++e) o[e] = rb[c * 8 + e];
        reinterpret_cast<ushort8*>(xnf)[(g16 * 16 + ks) * 64 + ln] = o;
    }
}

// ------------- kernel 2: transpose+convert kernel matrix, partial column sumsq -------
__global__ __launch_bounds__(256) void tcvt_k(const float* __restrict__ ker,
                                              unsigned short* __restrict__ kerbt,
                                              float* __restrict__ ssq) {
    __shared__ float tile[64][65];
    __shared__ float sp[256];
    int t = threadIdx.x;
    int c0 = blockIdx.x * 64;
    int d0 = blockIdx.y * 64;
    int lc = t & 63;
    int dq = t >> 6;
    int gc = c0 + lc;
    bool valid = gc < KK;
    float ss = 0.f;
#pragma unroll
    for (int i = 0; i < 16; ++i) {
        int d = dq + i * 4;
        float v = valid ? ker[(size_t)(d0 + d) * KK + gc] : 0.f;
        tile[d][lc] = v;
        ss = fmaf(v, v, ss);
    }
    sp[t] = ss;
    __syncthreads();
    if (t < 64 && (c0 + t) < KK) {
        float tot = sp[t] + sp[t + 64] + sp[t + 128] + sp[t + 192];
        atomicAdd(&ssq[c0 + t], tot);
    }
#pragma unroll
    for (int j = 0; j < 2; ++j) {
        int l = t + 256 * j;
        int c = l >> 3;
        int dc = l & 7;
        ushort8 o;
#pragma unroll
        for (int e = 0; e < 8; ++e) o[e] = f2bf(tile[dc * 8 + e][c]);
        *reinterpret_cast<ushort8*>(&kerbt[(size_t)(c0 + c) * DD + d0 + dc * 8]) = o;
    }
}

// ---------------- kernel 3: target logits (label columns, fp32) ----------------
__global__ void target_k(const float* __restrict__ xn, const float* __restrict__ ker,
                         const float* __restrict__ ssq, const int* __restrict__ label,
                         float* __restrict__ tl) {
    int b = blockIdx.x;
    int lane = threadIdx.x; // 64
    int col = label[b];
    float acc = 0.f;
#pragma unroll
    for (int d = lane; d < DD; d += 64)
        acc = fmaf(xn[b * DD + d], ker[(size_t)d * KK + col], acc);
    for (int off = 32; off; off >>= 1) acc += __shfl_down(acc, off);
    if (lane == 0) {
        float c = acc * rsqrtf(ssq[col]);
        c = fminf(1.f, fmaxf(-1.f, c));
        tl[b] = c;
    }
}

// ------- kernel 4: scalars (t_new, cos_theta_m, final target) + ssq pad fix -------
__global__ void scalar_k(const float* __restrict__ tl, const float* __restrict__ t_in,
                         float* __restrict__ ctm, float* __restrict__ ftl,
                         float* __restrict__ tnew, float* __restrict__ ssq) {
    int t = threadIdx.x; // 512
    float v = tl[t];
    __shared__ float red[8];
    __shared__ float s_tn;
    float s = v;
    for (int off = 32; off; off >>= 1) s += __shfl_down(s, off);
    if ((t & 63) == 0) red[t >> 6] = s;
    __syncthreads();
    if (t == 0) {
        float tot = 0.f;
        for (int i = 0; i < 8; ++i) tot += red[i];
        s_tn = (tot / 512.0f) * 0.01f + 0.99f * t_in[0];
        tnew[0] = s_tn;
    }
    __syncthreads();
    float st = sqrtf(fmaxf(0.f, 1.f - v * v));
    float cm = v * COS_Mf - st * SIN_Mf;
    ctm[t] = cm;
    ftl[t] = (v > THRESHf) ? cm : (v - MMf);
    if (t < KPAD - KK) ssq[KK + t] = 1.f;   // pad cols: kerbt rows are 0 -> logit 0
}

// ---- kernel 5: A-in-registers (32 rows/wave) streaming GEMM + fused epilogue ----
// grid = 512 blocks: h = blk>>8 (row half), s = blk&255 (panel stream).
// Block = 8 waves x 32 rows = 256 rows; B panels (64 cols x 512 k) double-buffered
// in LDS, staged once per row-half device-wide.  a_reg = 128 VGPR/wave.
// amdgpu_waves_per_eu(2,2): pin occupancy so the allocator uses the full
// 256-VGPR budget instead of spilling/rematerializing a_reg (round-5 failure).
#define BNp 64
#define NPAN (KPAD / BNp)       /* 1460 */
#define NSTR 256

__global__ __launch_bounds__(512)
__attribute__((amdgpu_waves_per_eu(2, 2))) void gemm_k(
    const __bf16* __restrict__ xnf,            // A fragments (fragment-order)
    const unsigned short* __restrict__ kerbt,  // [KPAD][512] bf16
    const float* __restrict__ ssq,
    const int* __restrict__ label,
    const float* __restrict__ ctm, const float* __restrict__ ftl,
    const float* __restrict__ tnew,
    float* __restrict__ gse, float* __restrict__ gsl)
{
    __shared__ __align__(16) unsigned short Bs[2][BNp * DD];  // 2 x 64 KB
    __shared__ float ctm_s[256], ftl_s[256];
    __shared__ int   lbl_s[256];

    const int t = threadIdx.x;        // 512
    const int lane = t & 63;
    const int w = t >> 6;             // wave owns rows h*256 + w*32 .. +31
    const int h = blockIdx.x >> 8;    // row half (0/1)
    const int s = blockIdx.x & 255;   // panel stream
    const int cp0 = lane & 15;
    const int kq = lane >> 4;
    const int np = (s < NPAN - 5 * NSTR) ? 6 : 5;   // panels in this stream

    if (t < 256) {
        int r = h * 256 + t;
        ctm_s[t] = ctm[r]; ftl_s[t] = ftl[r]; lbl_s[t] = label[r];
    }
    const float tn = tnew[0];

    // ---- A fragments: 32 rows x 512 k per wave = 128 VGPRs, loaded once ----
    bf16x8 a_reg[2][16];
    {
        const bf16x8* xf = reinterpret_cast<const bf16x8*>(xnf);
        const int g0 = h * 16 + w * 2;
#pragma unroll
        for (int i = 0; i < 2; ++i)
#pragma unroll
            for (int ks = 0; ks < 16; ++ks)
                a_reg[i][ks] = xf[((g0 + i) * 16 + ks) * 64 + lane];
    }
    // force materialization (discourage per-panel rematerialization/spill)
#pragma unroll
    for (int i = 0; i < 2; ++i)
#pragma unroll
        for (int ks = 0; ks < 16; ++ks)
            asm volatile("" :: "v"(__builtin_bit_cast(f32x4, a_reg[i][ks])));
    __builtin_amdgcn_sched_barrier(0);

    // ---- prologue: stage panel s -> buf0, ssq for s, panel s+256 -> buf1 ----
#pragma unroll
    for (int j = 0; j < 8; ++j) {
        int l = t + 512 * j;              // 0..4095 16B-chunks
        int c = l >> 6, kc = l & 63;
        int kcs = kc ^ (c & 7);           // source pre-swizzle
        gload16(&kerbt[(size_t)(s * BNp + c) * DD + kcs * 8], (void*)&Bs[0][l * 8]);
    }
    float sqN[4];
#pragma unroll
    for (int fc = 0; fc < 4; ++fc) sqN[fc] = ssq[s * BNp + fc * 16 + cp0];
    if (np > 1) {
#pragma unroll
        for (int j = 0; j < 8; ++j) {
            int l = t + 512 * j;
            int c = l >> 6, kc = l & 63;
            int kcs = kc ^ (c & 7);
            gload16(&kerbt[(size_t)((s + NSTR) * BNp + c) * DD + kcs * 8],
                    (void*)&Bs[1][l * 8]);
        }
        __builtin_amdgcn_sched_barrier(0);
        asm volatile("s_waitcnt vmcnt(8)" ::: "memory");
    } else {
        __builtin_amdgcn_sched_barrier(0);
        asm volatile("s_waitcnt vmcnt(0)" ::: "memory");
    }
    float inv4[4];
#pragma unroll
    for (int fc = 0; fc < 4; ++fc) inv4[fc] = rsqrtf(sqN[fc]);
    __builtin_amdgcn_s_barrier();

    float regse[2][4], regsl[2][4];
#pragma unroll
    for (int i = 0; i < 2; ++i)
#pragma unroll
        for (int r = 0; r < 4; ++r) { regse[i][r] = 0.f; regsl[i][r] = 0.f; }

    int buf = 0;
    for (int pi = 0; pi < np; ++pi) {
        const int col0 = (s + pi * NSTR) * BNp;   // current panel
        // 1. prefetch next panel's ssq (drained by this iter's vmcnt(8))
        if (pi + 1 < np) {
            const int cn0 = (s + (pi + 1) * NSTR) * BNp;
#pragma unroll
            for (int fc = 0; fc < 4; ++fc) sqN[fc] = ssq[cn0 + fc * 16 + cp0];
        }

        // 2. compute panel: 128 MFMA + 64 ds_read_b128 per wave
        f32x4 acc[2][4];
#pragma unroll
        for (int i = 0; i < 2; ++i)
#pragma unroll
            for (int fc = 0; fc < 4; ++fc) acc[i][fc] = (f32x4)0.f;

        const char* Bp = (const char*)&Bs[buf][0];
        __builtin_amdgcn_s_setprio(1);
#pragma unroll
        for (int ks = 0; ks < 16; ++ks) {
            bf16x8 bfr[4];
#pragma unroll
            for (int fc = 0; fc < 4; ++fc) {
                int cp = fc * 16 + cp0;
                int kk = ks * 4 + kq;
                int off = cp * 1024 + ((kk ^ (cp & 7)) * 16);  // read-side swizzle
                bfr[fc] = *reinterpret_cast<const bf16x8*>(Bp + off);
            }
#pragma unroll
            for (int i = 0; i < 2; ++i)
#pragma unroll
                for (int fc = 0; fc < 4; ++fc)
                    acc[i][fc] = __builtin_amdgcn_mfma_f32_16x16x32_bf16(
                        a_reg[i][ks], bfr[fc], acc[i][fc], 0, 0, 0);
        }
        __builtin_amdgcn_s_setprio(0);

        // fused CurricularFace transform; per-lane partials stay in registers
#pragma unroll
        for (int i = 0; i < 2; ++i) {
#pragma unroll
            for (int r = 0; r < 4; ++r) {
                const int rowl = w * 32 + i * 16 + (kq << 2) + r;
                float cm = ctm_s[rowl], ft = ftl_s[rowl];
                const int rel = lbl_s[rowl] - (col0 + cp0);  // label hit iff rel==fc*16
                float se = 0.f, sl = 0.f;
#pragma unroll
                for (int fc = 0; fc < 4; ++fc) {
                    float c = acc[i][fc][r] * inv4[fc];
                    c = fminf(1.f, fmaxf(-1.f, c));
                    float v = (c > cm) ? c * (tn + c) : c;
                    if (rel == fc * 16) v = ft;
                    float lg = S_SCALEf * v;
                    se += __expf(lg - MFIXf);
                    sl += lg;
                }
                regse[i][r] += se;
                regsl[i][r] += sl;
            }
        }

        // 3. all waves done reading buf -> safe to overwrite
        __builtin_amdgcn_s_barrier();
        if (pi + 2 < np) {
            const int cn0 = (s + (pi + 2) * NSTR) * BNp;
#pragma unroll
            for (int j = 0; j < 8; ++j) {
                int l = t + 512 * j;
                int c = l >> 6, kc = l & 63;
                int kcs = kc ^ (c & 7);
                gload16(&kerbt[(size_t)(cn0 + c) * DD + kcs * 8],
                        (void*)&Bs[buf][l * 8]);
            }
            __builtin_amdgcn_sched_barrier(0);
            asm volatile("s_waitcnt vmcnt(8)" ::: "memory");  // panel pi+1 landed
        } else if (pi + 1 < np) {
            asm volatile("s_waitcnt vmcnt(0)" ::: "memory");
        }
        if (pi + 1 < np) {
#pragma unroll
            for (int fc = 0; fc < 4; ++fc) inv4[fc] = rsqrtf(sqN[fc]);
            __builtin_amdgcn_s_barrier();
        }
        buf ^= 1;
    }

    // ---- block-end reduction: 16 lanes -> row, one global atomic per row ----
#pragma unroll
    for (int i = 0; i < 2; ++i) {
#pragma unroll
        for (int r = 0; r < 4; ++r) {
            float se = regse[i][r], sl = regsl[i][r];
#pragma unroll
            for (int off = 8; off; off >>= 1) {
                se += __shfl_down(se, off, 16);
                sl += __shfl_down(sl, off, 16);
            }
            if (cp0 == 0) {
                const int row = h * 256 + w * 32 + i * 16 + (kq << 2) + r;
                atomicAdd(&gse[row], se);
                atomicAdd(&gsl[row], sl);
            }
        }
    }
}

// ---------------- kernel 6: final loss ----------------
__global__ void loss_k(const float* __restrict__ gse, const float* __restrict__ gsl,
                       const float* __restrict__ ftl, float* __restrict__ out) {
    int t = threadIdx.x; // 512
    float lse = MFIXf + logf(gse[t]);
    float lbl_logit = S_SCALEf * ftl[t];
    float nll = (1.f - EPSf) * (lbl_logit - lse)
              + (EPSf / (float)KK) * (gsl[t] - (float)KK * lse);
    __shared__ float red[8];
    float s = nll;
    for (int off = 32; off; off >>= 1) s += __shfl_down(s, off);
    if ((t & 63) == 0) red[t >> 6] = s;
    __syncthreads();
    if (t == 0) {
        float tot = 0.f;
        for (int i = 0; i < 8; ++i) tot += red[i];
        out[0] = -(tot / 512.0f);
    }
}

extern "C" void kernel_launch(void* const* d_in, const int* in_sizes, int n_in,
                              void* d_out, int out_size, void* d_ws, size_t ws_size,
                              hipStream_t stream) {
    const float* x     = (const float*)d_in[0];
    const int*   label = (const int*)d_in[1];
    const float* ker   = (const float*)d_in[2];
    const float* t_in  = (const float*)d_in[3];
    float* out = (float*)d_out;

    float* ws   = (float*)d_ws;
    float* xn   = ws;                 // 262144 f32
    float* ssq  = xn + 262144;        // KPAD
    float* gse  = ssq + KPAD;         // 512
    float* gsl  = gse + 512;          // 512
    float* tl   = gsl + 512;          // 512
    float* ctm  = tl + 512;           // 512
    float* ftl  = ctm + 512;          // 512
    float* tnew = ftl + 512;          // 64
    unsigned short* xnf   = (unsigned short*)(tnew + 64);    // 262144 bf16 (frag order)
    unsigned short* kerbt = xnf + 262144;                    // KPAD*512 bf16

    hipMemsetAsync(ssq, 0, (KPAD + 1024) * sizeof(float), stream);

    rownorm_k<<<BB, 256, 0, stream>>>(x, xn, xnf);
    tcvt_k<<<dim3(KPAD / 64, DD / 64), 256, 0, stream>>>(ker, kerbt, ssq);
    target_k<<<BB, 64, 0, stream>>>(xn, ker, ssq, label, tl);
    scalar_k<<<1, 512, 0, stream>>>(tl, t_in, ctm, ftl, tnew, ssq);
    gemm_k<<<512, 512, 0, stream>>>((const __bf16*)xnf, kerbt, ssq, label,
                                    ctm, ftl, tnew, gse, gsl);
    loss_k<<<1, 512, 0, stream>>>(gse, gsl, ftl, out);
}

// Round 7
// 189.693 us; speedup vs baseline: 1.4036x; 1.1077x over previous
//
#include <hip/hip_runtime.h>
#include <math.h>

#define BB 512
#define DD 512
#define KK 93431
#define KPAD 93440

#define S_SCALEf 64.0f
#define COS_Mf   0.87758256189037276f   /* cos(0.5) */
#define SIN_Mf   0.47942553860420301f   /* sin(0.5) */
#define THRESHf (-0.87758256189037276f) /* cos(pi-0.5) */
#define MMf      0.23971276930210151f   /* sin(pi-0.5)*0.5 */
#define EPSf     0.1f
#define MFIXf    65.0f

typedef __bf16 bf16x8 __attribute__((ext_vector_type(8)));
typedef float  f32x4  __attribute__((ext_vector_type(4)));
typedef unsigned short ushort8 __attribute__((ext_vector_type(8)));

__device__ __forceinline__ unsigned short f2bf(float f) {
    union { float f; unsigned u; } v; v.f = f;
    unsigned r = v.u + 0x7FFFu + ((v.u >> 16) & 1u);   // RNE
    return (unsigned short)(r >> 16);
}

__device__ __forceinline__ void gload16(const void* g, void* l) {
    __builtin_amdgcn_global_load_lds(
        (const __attribute__((address_space(1))) unsigned int*)g,
        (__attribute__((address_space(3))) unsigned int*)l, 16, 0, 0);
}

// ---------------- kernel 1: row-normalize x -> xn (f32) + xnb (bf16) ----------------
__global__ void rownorm_k(const float* __restrict__ x, float* __restrict__ xn,
                          unsigned short* __restrict__ xnb) {
    int b = blockIdx.x;
    int t = threadIdx.x; // 256
    float v0 = x[b * DD + t];
    float v1 = x[b * DD + t + 256];
    float ss = v0 * v0 + v1 * v1;
    for (int off = 32; off; off >>= 1) ss += __shfl_down(ss, off);
    __shared__ float wred[4];
    __shared__ float s_inv;
    if ((t & 63) == 0) wred[t >> 6] = ss;
    __syncthreads();
    if (t == 0) s_inv = rsqrtf(wred[0] + wred[1] + wred[2] + wred[3]);
    __syncthreads();
    float inv = s_inv;
    float a0 = v0 * inv, a1 = v1 * inv;
    xn[b * DD + t]        = a0;
    xn[b * DD + t + 256]  = a1;
    xnb[b * DD + t]       = f2bf(a0);
    xnb[b * DD + t + 256] = f2bf(a1);
}

// ------------- kernel 2: transpose+convert kernel matrix, partial column sumsq -------
__global__ __launch_bounds__(256) void tcvt_k(const float* __restrict__ ker,
                                              unsigned short* __restrict__ kerbt,
                                              float* __restrict__ ssq) {
    __shared__ float tile[64][65];
    __shared__ float sp[256];
    int t = threadIdx.x;
    int c0 = blockIdx.x * 64;
    int d0 = blockIdx.y * 64;
    int lc = t & 63;
    int dq = t >> 6;
    int gc = c0 + lc;
    bool valid = gc < KK;
    float ss = 0.f;
#pragma unroll
    for (int i = 0; i < 16; ++i) {
        int d = dq + i * 4;
        float v = valid ? ker[(size_t)(d0 + d) * KK + gc] : 0.f;
        tile[d][lc] = v;
        ss = fmaf(v, v, ss);
    }
    sp[t] = ss;
    __syncthreads();
    if (t < 64 && (c0 + t) < KK) {
        float tot = sp[t] + sp[t + 64] + sp[t + 128] + sp[t + 192];
        atomicAdd(&ssq[c0 + t], tot);
    }
#pragma unroll
    for (int j = 0; j < 2; ++j) {
        int l = t + 256 * j;
        int c = l >> 3;
        int dc = l & 7;
        ushort8 o;
#pragma unroll
        for (int e = 0; e < 8; ++e) o[e] = f2bf(tile[dc * 8 + e][c]);
        *reinterpret_cast<ushort8*>(&kerbt[(size_t)(c0 + c) * DD + d0 + dc * 8]) = o;
    }
}

// ---------------- kernel 3: target logits (label columns, fp32) ----------------
__global__ void target_k(const float* __restrict__ xn, const float* __restrict__ ker,
                         const float* __restrict__ ssq, const int* __restrict__ label,
                         float* __restrict__ tl) {
    int b = blockIdx.x;
    int lane = threadIdx.x; // 64
    int col = label[b];
    float acc = 0.f;
#pragma unroll
    for (int d = lane; d < DD; d += 64)
        acc = fmaf(xn[b * DD + d], ker[(size_t)d * KK + col], acc);
    for (int off = 32; off; off >>= 1) acc += __shfl_down(acc, off);
    if (lane == 0) {
        float c = acc * rsqrtf(ssq[col]);
        c = fminf(1.f, fmaxf(-1.f, c));
        tl[b] = c;
    }
}

// ------- kernel 4: scalars (t_new, cos_theta_m, final target) + ssq pad fix -------
__global__ void scalar_k(const float* __restrict__ tl, const float* __restrict__ t_in,
                         float* __restrict__ ctm, float* __restrict__ ftl,
                         float* __restrict__ tnew, float* __restrict__ ssq) {
    int t = threadIdx.x; // 512
    float v = tl[t];
    __shared__ float red[8];
    __shared__ float s_tn;
    float s = v;
    for (int off = 32; off; off >>= 1) s += __shfl_down(s, off);
    if ((t & 63) == 0) red[t >> 6] = s;
    __syncthreads();
    if (t == 0) {
        float tot = 0.f;
        for (int i = 0; i < 8; ++i) tot += red[i];
        s_tn = (tot / 512.0f) * 0.01f + 0.99f * t_in[0];
        tnew[0] = s_tn;
    }
    __syncthreads();
    float st = sqrtf(fmaxf(0.f, 1.f - v * v));
    float cm = v * COS_Mf - st * SIN_Mf;
    ctm[t] = cm;
    ftl[t] = (v > THRESHf) ? cm : (v - MMf);
    if (t < KPAD - KK) ssq[KK + t] = 1.f;   // pad cols: kerbt rows are 0 -> logit 0
}

// ---- kernel 5: 128x128 tiled MFMA GEMM, counted-vmcnt dbuf, 2 blocks/CU ----
// 512 thr = 8 waves (2 wm x 4 wn), wave = 64 rows x 32 cols, acc = 4x2 f32x4.
// LDS: 2x16KB A + 2x16KB B + ~3KB epilogue = 67KB -> 2 blocks/CU, 16 waves/CU.
#define TMt 128
#define TNt 128
#define BKt 64
#define NWG ((KPAD / TNt) * (BB / TMt))   /* 730 * 4 = 2920 */

__global__ __launch_bounds__(512) void gemm_k(
    const unsigned short* __restrict__ xnb,    // [512][512] bf16 row-major
    const unsigned short* __restrict__ kerbt,  // [KPAD][512] bf16 row-major
    const float* __restrict__ ssq,
    const int* __restrict__ label,
    const float* __restrict__ ctm, const float* __restrict__ ftl,
    const float* __restrict__ tnew,
    float* __restrict__ gse, float* __restrict__ gsl)
{
    __shared__ __align__(16) unsigned short As[2][TMt * BKt];  // 2 x 16 KB
    __shared__ __align__(16) unsigned short Bs[2][TNt * BKt];  // 2 x 16 KB
    __shared__ float se_s[TMt], sl_s[TMt], ctm_s[TMt], ftl_s[TMt];
    __shared__ int   lbl_s[TMt];

    // bijective XCD swizzle (2920 % 8 == 0); row-block-inner decomposition
    int wg = blockIdx.x;
    int id = (wg & 7) * (NWG / 8) + (wg >> 3);
    int by = id & 3;                   // 4 row-blocks of a col-tile adjacent
    int bx = id >> 2;
    int row0 = by * TMt;
    int col0 = bx * TNt;

    const int t = threadIdx.x;         // 512
    const int lane = t & 63;
    const int w = t >> 6;
    const int wm = w >> 2;             // 0..1  (64-row slice)
    const int wn = w & 3;              // 0..3  (32-col slice)
    const int cp0 = lane & 15;
    const int kq = lane >> 4;

    if (t < TMt) {
        se_s[t] = 0.f; sl_s[t] = 0.f;
        int r = row0 + t;
        ctm_s[t] = ctm[r]; ftl_s[t] = ftl[r]; lbl_s[t] = label[r];
    }
    const float tn = tnew[0];

    // prologue ssq loads (consumed only in epilogue; drained long before use)
    float sq2[2];
#pragma unroll
    for (int fc = 0; fc < 2; ++fc)
        sq2[fc] = ssq[col0 + wn * 32 + fc * 16 + cp0];

    // ---- staging helper pattern: 4 gload16/thread per k-step (2 A + 2 B) ----
    // dest chunk l in [0,1024): r = l>>3, kc = l&7; source pre-swizzled kc^(r&7).
#define STAGE(kt, bi)                                                          \
    {                                                                          \
        const int k0 = (kt) * BKt;                                             \
        _Pragma("unroll")                                                      \
        for (int j = 0; j < 2; ++j) {                                          \
            int l = t + 512 * j;                                               \
            int r = l >> 3, kc = l & 7;                                        \
            int kcs = kc ^ (r & 7);                                            \
            gload16(&xnb[(size_t)(row0 + r) * DD + k0 + kcs * 8],              \
                    (void*)&As[bi][l * 8]);                                    \
        }                                                                      \
        _Pragma("unroll")                                                      \
        for (int j = 0; j < 2; ++j) {                                          \
            int l = t + 512 * j;                                               \
            int c = l >> 3, kc = l & 7;                                        \
            int kcs = kc ^ (c & 7);                                            \
            gload16(&kerbt[(size_t)(col0 + c) * DD + k0 + kcs * 8],            \
                    (void*)&Bs[bi][l * 8]);                                    \
        }                                                                      \
    }

    STAGE(0, 0);
    STAGE(1, 1);
    __builtin_amdgcn_sched_barrier(0);
    asm volatile("s_waitcnt vmcnt(4)" ::: "memory");   // tile 0 landed
    __builtin_amdgcn_s_barrier();

    f32x4 acc[4][2];
#pragma unroll
    for (int fm = 0; fm < 4; ++fm)
#pragma unroll
        for (int fc = 0; fc < 2; ++fc) acc[fm][fc] = (f32x4)0.f;

    for (int kt = 0; kt < 8; ++kt) {
        const int bi = kt & 1;
        const char* Ap = (const char*)&As[bi][0];
        const char* Bp = (const char*)&Bs[bi][0];
#pragma unroll
        for (int ks = 0; ks < 2; ++ks) {
            bf16x8 bfr[2];
#pragma unroll
            for (int fc = 0; fc < 2; ++fc) {
                int ct = wn * 32 + fc * 16 + cp0;
                int kc = ks * 4 + kq;
                bfr[fc] = *reinterpret_cast<const bf16x8*>(
                    Bp + ct * 128 + ((kc ^ (ct & 7)) * 16));
            }
#pragma unroll
            for (int fm = 0; fm < 4; ++fm) {
                int rt = wm * 64 + fm * 16 + cp0;
                int kc = ks * 4 + kq;
                bf16x8 af = *reinterpret_cast<const bf16x8*>(
                    Ap + rt * 128 + ((kc ^ (rt & 7)) * 16));
                acc[fm][0] = __builtin_amdgcn_mfma_f32_16x16x32_bf16(
                    af, bfr[0], acc[fm][0], 0, 0, 0);
                acc[fm][1] = __builtin_amdgcn_mfma_f32_16x16x32_bf16(
                    af, bfr[1], acc[fm][1], 0, 0, 0);
            }
        }
        __builtin_amdgcn_s_barrier();          // all waves done reading buf bi
        if (kt + 2 < 8) {
            STAGE(kt + 2, bi);
            __builtin_amdgcn_sched_barrier(0);
            asm volatile("s_waitcnt vmcnt(4)" ::: "memory");  // tile kt+1 landed
        } else if (kt + 1 < 8) {
            asm volatile("s_waitcnt vmcnt(0)" ::: "memory");
        }
        if (kt + 1 < 8) __builtin_amdgcn_s_barrier();
    }
#undef STAGE

    // ---- fused CurricularFace epilogue (once per block, full-K acc) ----
    float inv2[2];
#pragma unroll
    for (int fc = 0; fc < 2; ++fc) inv2[fc] = rsqrtf(sq2[fc]);

#pragma unroll
    for (int fm = 0; fm < 4; ++fm) {
#pragma unroll
        for (int reg = 0; reg < 4; ++reg) {
            const int rt = wm * 64 + fm * 16 + (kq << 2) + reg;  // block-local row
            float cm = ctm_s[rt], ft = ftl_s[rt];
            const int rel = lbl_s[rt] - (col0 + wn * 32 + cp0);
            float se = 0.f, sl = 0.f;
#pragma unroll
            for (int fc = 0; fc < 2; ++fc) {
                float c = acc[fm][fc][reg] * inv2[fc];
                c = fminf(1.f, fmaxf(-1.f, c));
                float v = (c > cm) ? c * (tn + c) : c;
                if (rel == fc * 16) v = ft;
                float lg = S_SCALEf * v;
                se += __expf(lg - MFIXf);
                sl += lg;
            }
#pragma unroll
            for (int off = 8; off; off >>= 1) {
                se += __shfl_down(se, off, 16);
                sl += __shfl_down(sl, off, 16);
            }
            if (cp0 == 0) {
                atomicAdd(&se_s[rt], se);
                atomicAdd(&sl_s[rt], sl);
            }
        }
    }
    __syncthreads();
    if (t < TMt) {
        atomicAdd(&gse[row0 + t], se_s[t]);
        atomicAdd(&gsl[row0 + t], sl_s[t]);
    }
}

// ---------------- kernel 6: final loss ----------------
__global__ void loss_k(const float* __restrict__ gse, const float* __restrict__ gsl,
                       const float* __restrict__ ftl, float* __restrict__ out) {
    int t = threadIdx.x; // 512
    float lse = MFIXf + logf(gse[t]);
    float lbl_logit = S_SCALEf * ftl[t];
    float nll = (1.f - EPSf) * (lbl_logit - lse)
              + (EPSf / (float)KK) * (gsl[t] - (float)KK * lse);
    __shared__ float red[8];
    float s = nll;
    for (int off = 32; off; off >>= 1) s += __shfl_down(s, off);
    if ((t & 63) == 0) red[t >> 6] = s;
    __syncthreads();
    if (t == 0) {
        float tot = 0.f;
        for (int i = 0; i < 8; ++i) tot += red[i];
        out[0] = -(tot / 512.0f);
    }
}

extern "C" void kernel_launch(void* const* d_in, const int* in_sizes, int n_in,
                              void* d_out, int out_size, void* d_ws, size_t ws_size,
                              hipStream_t stream) {
    const float* x     = (const float*)d_in[0];
    const int*   label = (const int*)d_in[1];
    const float* ker   = (const float*)d_in[2];
    const float* t_in  = (const float*)d_in[3];
    float* out = (float*)d_out;

    float* ws   = (float*)d_ws;
    float* xn   = ws;                 // 262144 f32
    float* ssq  = xn + 262144;        // KPAD
    float* gse  = ssq + KPAD;         // 512
    float* gsl  = gse + 512;          // 512
    float* tl   = gsl + 512;          // 512
    float* ctm  = tl + 512;           // 512
    float* ftl  = ctm + 512;          // 512
    float* tnew = ftl + 512;          // 64
    unsigned short* xnb   = (unsigned short*)(tnew + 64);    // 262144 bf16
    unsigned short* kerbt = xnb + 262144;                    // KPAD*512 bf16

    hipMemsetAsync(ssq, 0, (KPAD + 1024) * sizeof(float), stream);

    rownorm_k<<<BB, 256, 0, stream>>>(x, xn, xnb);
    tcvt_k<<<dim3(KPAD / 64, DD / 64), 256, 0, stream>>>(ker, kerbt, ssq);
    target_k<<<BB, 64, 0, stream>>>(xn, ker, ssq, label, tl);
    scalar_k<<<1, 512, 0, stream>>>(tl, t_in, ctm, ftl, tnew, ssq);
    gemm_k<<<NWG, 512, 0, stream>>>(xnb, kerbt, ssq, label, ctm, ftl, tnew, gse, gsl);
    loss_k<<<1, 512, 0, stream>>>(gse, gsl, ftl, out);
}